// Round 6
// baseline (360.255 us; speedup 1.0000x reference)
//
#include <hip/hip_runtime.h>
#include <hip/hip_bf16.h>
#include <math.h>

// ---------------------------------------------------------------------------
// Attention_17231408791684: x->QKV (bias) -> RoPE -> sliding-window(128)
// causal attention w/ sinks -> O-proj (bias).  f32 in/out, bf16 compute.
// Round 6: split-K=2 qkv (1280 blocks, reduce fused into rope) +
// split-K=3 oproj (1104 blocks). Fallback to whole-K qkv if ws too small.
// ---------------------------------------------------------------------------

typedef __bf16 bf16x8 __attribute__((ext_vector_type(8)));
typedef float  f32x4  __attribute__((ext_vector_type(4)));

#define MFMA_BF16(a,b,c) __builtin_amdgcn_mfma_f32_16x16x32_bf16((a),(b),(c),0,0,0)

// workspace element offsets (bf16 elements)
#define XB   0L
#define WQB  5898240L
#define WKB  17694720L
#define WVB  19169280L
#define WOB  20643840L
#define QB   32440320L
#define KB   40828928L
#define VB   41877504L
#define PQ0  42926080L
#define PK0  51314688L
#define PV0  52363264L
#define SPLIT_BYTES 106823680UL   // (PV0 + 1048576) * 2

__device__ __forceinline__ void gld_lds16(const void* g, void* l) {
    __builtin_amdgcn_global_load_lds(
        (__attribute__((address_space(1))) void*)(g),
        (__attribute__((address_space(3))) void*)(l), 16, 0, 0);
}

__device__ __forceinline__ bf16x8 ld8f(const float* p) {
    f32x4 a = *(const f32x4*)p;
    f32x4 b = *(const f32x4*)(p + 4);
    bf16x8 r;
#pragma unroll
    for (int t = 0; t < 4; t++) { r[t] = (__bf16)a[t]; r[t + 4] = (__bf16)b[t]; }
    return r;
}

// ---------------------------------------------------------------------------
// f32 -> bf16 conversion of {x, wq, wk, wv, wo}; 8 elems/thread, 15840x256.
// ---------------------------------------------------------------------------
__global__ __launch_bounds__(256) void convert_kernel(
    const float* __restrict__ x,  const float* __restrict__ wq,
    const float* __restrict__ wk, const float* __restrict__ wv,
    const float* __restrict__ wo, __bf16* __restrict__ dst)
{
    long e = ((long)blockIdx.x * 256 + threadIdx.x) * 8;
    const float* src; long off;
    if      (e <  WQB) { src = x;  off = e; }
    else if (e <  WKB) { src = wq; off = e - WQB; }
    else if (e <  WVB) { src = wk; off = e - WKB; }
    else if (e <  WOB) { src = wv; off = e - WVB; }
    else               { src = wo; off = e - WOB; }
    *(bf16x8*)(dst + e) = ld8f(src + off);
}

// ---------------------------------------------------------------------------
// NT GEMM, BK=64, k in [kBeg,kEnd). 128x128 tile, 256 thr (2x2 waves of
// 64x64). LDS [2][128][32]/operand. bias==nullptr -> none.
// ---------------------------------------------------------------------------
__device__ __forceinline__ void gemm_block64(
    const __bf16* __restrict__ A, const __bf16* __restrict__ W,
    const float* __restrict__ bias, __bf16* __restrict__ C,
    int N, int Ks, int kBeg, int kEnd, int m0, int n0,
    __bf16* As, __bf16* Bs)
{
    const int tid  = threadIdx.x;
    const int lane = tid & 63;
    const int wv   = tid >> 6;
    const int wm   = (wv >> 1) * 64;
    const int wn   = (wv & 1) * 64;
    const int quad = lane >> 4;
    const int c    = lane & 15;

    const int srow = tid >> 2;          // 0..63
    const int scol = (tid & 3) * 8;     // 0,8,16,24

    int br0 = n0 + srow;      if (br0 > N - 1) br0 = N - 1;
    int br1 = n0 + 64 + srow; if (br1 > N - 1) br1 = N - 1;
    const __bf16* pa0 = A + (size_t)(m0 + srow) * Ks + scol;
    const __bf16* pa1 = A + (size_t)(m0 + 64 + srow) * Ks + scol;
    const __bf16* pb0 = W + (size_t)br0 * Ks + scol;
    const __bf16* pb1 = W + (size_t)br1 * Ks + scol;

    f32x4 acc[4][4];
#pragma unroll
    for (int i = 0; i < 4; i++)
#pragma unroll
        for (int j = 0; j < 4; j++) acc[i][j] = (f32x4){0.f, 0.f, 0.f, 0.f};

    for (int kk = kBeg; kk < kEnd; kk += 64) {
        gld_lds16(pa0 + kk,      As + tid * 8);
        gld_lds16(pa1 + kk,      As + 2048 + tid * 8);
        gld_lds16(pa0 + kk + 32, As + 4096 + tid * 8);
        gld_lds16(pa1 + kk + 32, As + 6144 + tid * 8);
        gld_lds16(pb0 + kk,      Bs + tid * 8);
        gld_lds16(pb1 + kk,      Bs + 2048 + tid * 8);
        gld_lds16(pb0 + kk + 32, Bs + 4096 + tid * 8);
        gld_lds16(pb1 + kk + 32, Bs + 6144 + tid * 8);
        __syncthreads();
        for (int kt = 0; kt < 2; kt++) {
            bf16x8 af[4], bfv[4];
#pragma unroll
            for (int i = 0; i < 4; i++)
                af[i] = *(const bf16x8*)&As[kt * 4096 + (wm + i * 16 + c) * 32 + quad * 8];
#pragma unroll
            for (int j = 0; j < 4; j++)
                bfv[j] = *(const bf16x8*)&Bs[kt * 4096 + (wn + j * 16 + c) * 32 + quad * 8];
#pragma unroll
            for (int i = 0; i < 4; i++)
#pragma unroll
                for (int j = 0; j < 4; j++)
                    acc[i][j] = MFMA_BF16(af[i], bfv[j], acc[i][j]);
        }
        __syncthreads();
    }

#pragma unroll
    for (int j = 0; j < 4; j++) {
        int col = n0 + wn + j * 16 + c;
        if (col >= N) continue;
        float bv = bias ? bias[col] : 0.0f;
#pragma unroll
        for (int i = 0; i < 4; i++) {
            int row = m0 + wm + i * 16 + quad * 4;
#pragma unroll
            for (int r = 0; r < 4; r++)
                C[(size_t)(row + r) * N + col] = (__bf16)(acc[i][j][r] + bv);
        }
    }
}

// Fused QKV. mode 0: whole-K (z==0 only), bias, write final.
// mode 1: z=0 -> partial buffers [0,z0End), no bias; z=1 -> final, [z0End,K).
__global__ __launch_bounds__(256, 3) void qkv_kernel(
    const __bf16* __restrict__ x,
    const __bf16* __restrict__ wq, const float* __restrict__ bq,
    const __bf16* __restrict__ wk, const float* __restrict__ bk,
    const __bf16* __restrict__ wv, const float* __restrict__ bv,
    __bf16* __restrict__ qo, __bf16* __restrict__ ko, __bf16* __restrict__ vo,
    __bf16* __restrict__ pq, __bf16* __restrict__ pk, __bf16* __restrict__ pv,
    int z0End, int mode)
{
    __shared__ __align__(16) __bf16 As[8192], Bs[8192];
    const int by = blockIdx.y, z = blockIdx.z;
    const __bf16 *W; const float* bias; __bf16 *Cf, *Cp; int N, n0;
    if (by < 32)      { W = wq; bias = bq; Cf = qo; Cp = pq; N = 4096; n0 = by * 128; }
    else if (by < 36) { W = wk; bias = bk; Cf = ko; Cp = pk; N = 512;  n0 = (by - 32) * 128; }
    else              { W = wv; bias = bv; Cf = vo; Cp = pv; N = 512;  n0 = (by - 36) * 128; }
    __bf16* C; const float* bu; int kB, kE;
    if (mode == 0)    { C = Cf; bu = bias;    kB = 0;     kE = 2880; }
    else if (z == 0)  { C = Cp; bu = nullptr; kB = 0;     kE = z0End; }
    else              { C = Cf; bu = nullptr; kB = z0End; kE = 2880; }
    gemm_block64(x, W, bu, C, N, 2880, kB, kE, blockIdx.x * 128, n0, As, Bs);
}

// O-proj split-K=3 partials: grid (16,23,3); k in [zB[z], zB[z+1])
__global__ __launch_bounds__(256, 3) void oproj_kernel(
    const __bf16* __restrict__ a, const __bf16* __restrict__ w,
    __bf16* __restrict__ p0, __bf16* __restrict__ p1, __bf16* __restrict__ p2)
{
    __shared__ __align__(16) __bf16 As[8192], Bs[8192];
    const int z = blockIdx.z;
    __bf16* C = (z == 0) ? p0 : (z == 1) ? p1 : p2;
    const int kB = (z == 0) ? 0 : (z == 1) ? 1408 : 2816;
    const int kE = (z == 0) ? 1408 : (z == 1) ? 2816 : 4096;
    gemm_block64(a, w, nullptr, C, 2880, 4096, kB, kE,
                 blockIdx.x * 128, blockIdx.y * 128, As, Bs);
}

// out[e] = p0+p1+p2+bias; 8 elems/thread, grid 2880x256 exact.
__global__ __launch_bounds__(256) void reduce3_kernel(
    const __bf16* __restrict__ p0, const __bf16* __restrict__ p1,
    const __bf16* __restrict__ p2, const float* __restrict__ bo,
    float* __restrict__ out)
{
    long e = ((long)blockIdx.x * 256 + threadIdx.x) * 8;
    int col = (int)(e % 2880L);          // 2880 % 8 == 0
    bf16x8 a = *(const bf16x8*)(p0 + e);
    bf16x8 b = *(const bf16x8*)(p1 + e);
    bf16x8 d = *(const bf16x8*)(p2 + e);
    f32x4 o0, o1;
#pragma unroll
    for (int t = 0; t < 4; t++) {
        o0[t] = (float)a[t] + (float)b[t] + (float)d[t] + bo[col + t];
        o1[t] = (float)a[4+t] + (float)b[4+t] + (float)d[4+t] + bo[col + 4 + t];
    }
    *(f32x4*)(out + e)     = o0;
    *(f32x4*)(out + e + 4) = o1;
}

// ---------------------------------------------------------------------------
// Fused qkv split-K reduce + bias + RoPE. Final buffers hold the z=1 partial;
// p* holds z=0. unit r<288: rope pair-unit (head=r>>2, dg=r&3); r>=288: v
// 16-elem unit. Grid 2560x256 exact (2048 s x 320 units).
// ---------------------------------------------------------------------------
__global__ __launch_bounds__(256) void reduce_rope_kernel(
    __bf16* __restrict__ qb, __bf16* __restrict__ kb, __bf16* __restrict__ vb,
    const __bf16* __restrict__ pq, const __bf16* __restrict__ pk,
    const __bf16* __restrict__ pv,
    const float* __restrict__ bq, const float* __restrict__ bk,
    const float* __restrict__ bv, const float* __restrict__ rope)
{
    int idx = blockIdx.x * 256 + threadIdx.x;
    int s   = idx / 320;
    int r   = idx % 320;
    if (r < 288) {
        int head = r >> 2, d0 = (r & 3) * 8;
        __bf16* f; const __bf16* p; const float* bias;
        if (head < 64) { f = qb + (size_t)s * 4096 + head * 64;
                         p = pq + (size_t)s * 4096 + head * 64;
                         bias = bq + head * 64; }
        else           { int kh = head - 64;
                         f = kb + (size_t)s * 512 + kh * 64;
                         p = pk + (size_t)s * 512 + kh * 64;
                         bias = bk + kh * 64; }
        bf16x8 f1 = *(const bf16x8*)(f + d0);
        bf16x8 f2 = *(const bf16x8*)(f + d0 + 32);
        bf16x8 p1 = *(const bf16x8*)(p + d0);
        bf16x8 p2 = *(const bf16x8*)(p + d0 + 32);
        const float* rc = rope + (size_t)s * 128 + d0;
        bf16x8 o1, o2;
#pragma unroll
        for (int t = 0; t < 8; t++) {
            float x1 = (float)f1[t] + (float)p1[t] + bias[d0 + t];
            float x2 = (float)f2[t] + (float)p2[t] + bias[d0 + 32 + t];
            float cc = rc[t], si = rc[64 + t];
            o1[t] = (__bf16)(x1 * cc - x2 * si);
            o2[t] = (__bf16)(x2 * cc + x1 * si);
        }
        *(bf16x8*)(f + d0)      = o1;
        *(bf16x8*)(f + d0 + 32) = o2;
    } else {
        int e0 = (r - 288) * 16;                   // 0..496
        size_t e = (size_t)s * 512 + e0;
#pragma unroll
        for (int half = 0; half < 2; half++) {
            bf16x8 a = *(const bf16x8*)(vb + e + half * 8);
            bf16x8 b = *(const bf16x8*)(pv + e + half * 8);
            bf16x8 o;
#pragma unroll
            for (int t = 0; t < 8; t++)
                o[t] = (__bf16)((float)a[t] + (float)b[t] + bv[e0 + half * 8 + t]);
            *(bf16x8*)(vb + e + half * 8) = o;
        }
    }
}

// Plain RoPE (fallback path, whole-K qkv already has bias applied).
__global__ __launch_bounds__(256) void rope_kernel(
    __bf16* __restrict__ qb, __bf16* __restrict__ kb,
    const float* __restrict__ rope)
{
    int idx  = blockIdx.x * 256 + threadIdx.x;   // 2048*72*4 exact
    int dg   = idx & 3;
    int head = (idx >> 2) % 72;
    int s    = (idx >> 2) / 72;
    __bf16* p = (head < 64) ? (qb + (size_t)s * 4096 + head * 64)
                            : (kb + (size_t)s * 512 + (size_t)(head - 64) * 64);
    int d0 = dg * 8;
    bf16x8 x1 = *(bf16x8*)(p + d0);
    bf16x8 x2 = *(bf16x8*)(p + d0 + 32);
    const float* rc = rope + (size_t)s * 128 + d0;
    bf16x8 o1, o2;
#pragma unroll
    for (int t = 0; t < 8; t++) {
        float cc = rc[t], si = rc[64 + t];
        float a = (float)x1[t], b = (float)x2[t];
        o1[t] = (__bf16)(a * cc - b * si);
        o2[t] = (__bf16)(b * cc + a * si);
    }
    *(bf16x8*)(p + d0)      = o1;
    *(bf16x8*)(p + d0 + 32) = o2;
}

// ---------------------------------------------------------------------------
// Attention, IN-PLACE on q. block = (64-query tile, head); wave w owns q rows
// [w*16,w*16+16) x all 192 staged keys. Softmax wave-local (shfl over c).
// LDS: Qs[64][72]@0, Ks[192][72]@9216, Vt[64][208]@36864; P overlays @0.
// ---------------------------------------------------------------------------
__global__ __launch_bounds__(256) void attn_kernel(
    __bf16* __restrict__ q, const __bf16* __restrict__ k,
    const __bf16* __restrict__ v, const float* __restrict__ sinks)
{
    __shared__ __align__(16) char smem[63488];
    __bf16* Qs = (__bf16*)smem;
    __bf16* Ks = (__bf16*)(smem + 9216);
    __bf16* Vt = (__bf16*)(smem + 36864);
    __bf16* P  = (__bf16*)smem;

    const int tid = threadIdx.x, lane = tid & 63, w = tid >> 6;
    const int quad = lane >> 4, c = lane & 15;
    const int i0 = blockIdx.x * 64;
    const int h  = blockIdx.y;
    const int kvh = h >> 3;
    const int k0 = i0 - 128;

    {
        const int row = tid >> 3;
        const int col = (tid & 7) * 8;
#pragma unroll
        for (int it = 0; it < 2; it++) {
            int r2 = row + it * 32;
            bf16x8 t = *(const bf16x8*)(q + (size_t)(i0 + r2) * 4096 + h * 64 + col);
            *(bf16x8*)&Qs[r2 * 72 + col] = t;
        }
#pragma unroll
        for (int it = 0; it < 6; it++) {
            int r2 = row + it * 32;
            int j = k0 + r2; if (j < 0) j = 0;
            bf16x8 t = *(const bf16x8*)(k + (size_t)j * 512 + kvh * 64 + col);
            *(bf16x8*)&Ks[r2 * 72 + col] = t;
        }
        const int vrow = tid & 31;
        const int d0 = (tid >> 5) * 8;
#pragma unroll
        for (int it = 0; it < 6; it++) {
            int r2 = vrow + it * 32;
            int j = k0 + r2; if (j < 0) j = 0;
            bf16x8 t = *(const bf16x8*)(v + (size_t)j * 512 + kvh * 64 + d0);
#pragma unroll
            for (int u = 0; u < 8; u++) Vt[(d0 + u) * 208 + r2] = t[u];
        }
    }
    __syncthreads();

    f32x4 acc[12];
#pragma unroll
    for (int j = 0; j < 12; j++) acc[j] = (f32x4){0.f, 0.f, 0.f, 0.f};
#pragma unroll
    for (int kt = 0; kt < 2; kt++) {
        bf16x8 af = *(const bf16x8*)&Qs[(w * 16 + c) * 72 + kt * 32 + quad * 8];
#pragma unroll
        for (int j = 0; j < 12; j++) {
            bf16x8 bv = *(const bf16x8*)&Ks[(j * 16 + c) * 72 + kt * 32 + quad * 8];
            acc[j] = MFMA_BF16(af, bv, acc[j]);
        }
    }
    __syncthreads();

    const float scale = 0.16832169878499658f;
    const int igb = i0 + w * 16 + quad * 4;
    float rmax[4] = {-3.0e4f, -3.0e4f, -3.0e4f, -3.0e4f};
#pragma unroll
    for (int j = 0; j < 12; j++) {
        int jg = k0 + j * 16 + c;
#pragma unroll
        for (int r = 0; r < 4; r++) {
            int ig = igb + r;
            bool ok = (jg >= 0) && (jg <= ig) && (ig - jg < 128);
            float vv = ok ? acc[j][r] * scale : -3.0e4f;
            acc[j][r] = vv;
            rmax[r] = fmaxf(rmax[r], vv);
        }
    }
#pragma unroll
    for (int off = 1; off < 16; off <<= 1)
#pragma unroll
        for (int r = 0; r < 4; r++)
            rmax[r] = fmaxf(rmax[r], __shfl_xor(rmax[r], off));

    float rs[4] = {0.f, 0.f, 0.f, 0.f};
#pragma unroll
    for (int j = 0; j < 12; j++)
#pragma unroll
        for (int r = 0; r < 4; r++) {
            float e = __expf(acc[j][r] - rmax[r]);
            acc[j][r] = e;
            rs[r] += e;
        }
#pragma unroll
    for (int off = 1; off < 16; off <<= 1)
#pragma unroll
        for (int r = 0; r < 4; r++)
            rs[r] += __shfl_xor(rs[r], off);

    float rowfac[4];
    {
        float sk = sinks[h];
#pragma unroll
        for (int r = 0; r < 4; r++) {
            float s = fmaxf(rs[r], 1e-20f);
            float lse = rmax[r] + __logf(s);
            rowfac[r] = 1.f / ((1.f + __expf(sk - lse)) * s);
        }
    }

#pragma unroll
    for (int j = 0; j < 12; j++)
#pragma unroll
        for (int r = 0; r < 4; r++)
            P[(w * 16 + quad * 4 + r) * 208 + j * 16 + c] = (__bf16)acc[j][r];
    __syncthreads();

    f32x4 acc2[4];
#pragma unroll
    for (int jd = 0; jd < 4; jd++) acc2[jd] = (f32x4){0.f, 0.f, 0.f, 0.f};
#pragma unroll
    for (int kt = 0; kt < 6; kt++) {
        bf16x8 a = *(const bf16x8*)&P[(w * 16 + c) * 208 + kt * 32 + quad * 8];
#pragma unroll
        for (int jd = 0; jd < 4; jd++) {
            bf16x8 b = *(const bf16x8*)&Vt[(jd * 16 + c) * 208 + kt * 32 + quad * 8];
            acc2[jd] = MFMA_BF16(a, b, acc2[jd]);
        }
    }
#pragma unroll
    for (int jd = 0; jd < 4; jd++)
#pragma unroll
        for (int r = 0; r < 4; r++) {
            int qr = w * 16 + quad * 4 + r;
            q[(size_t)(i0 + qr) * 4096 + h * 64 + jd * 16 + c] =
                (__bf16)(acc2[jd][r] * rowfac[r]);
        }
}

// ---------------------------------------------------------------------------
extern "C" void kernel_launch(void* const* d_in, const int* in_sizes, int n_in,
                              void* d_out, int out_size, void* d_ws, size_t ws_size,
                              hipStream_t stream) {
    const float* x    = (const float*)d_in[0];
    const float* rope = (const float*)d_in[1];
    const float* wq   = (const float*)d_in[2];
    const float* bq   = (const float*)d_in[3];
    const float* wk   = (const float*)d_in[4];
    const float* bk   = (const float*)d_in[5];
    const float* wv   = (const float*)d_in[6];
    const float* bv   = (const float*)d_in[7];
    const float* wo   = (const float*)d_in[8];
    const float* bo   = (const float*)d_in[9];
    const float* sk   = (const float*)d_in[10];
    float* out = (float*)d_out;

    __bf16* wsb = (__bf16*)d_ws;
    __bf16* xb  = wsb + XB;
    __bf16* wqb = wsb + WQB;
    __bf16* wkb = wsb + WKB;
    __bf16* wvb = wsb + WVB;
    __bf16* wob = wsb + WOB;
    __bf16* qb  = wsb + QB;
    __bf16* kb  = wsb + KB;
    __bf16* vb  = wsb + VB;
    __bf16* pq0 = wsb + PQ0;           // qkv split-K z=0 partials
    __bf16* pk0 = wsb + PK0;
    __bf16* pv0 = wsb + PV0;
    __bf16* po0 = wsb + 0L;            // oproj partials overlay dead xb/wqb
    __bf16* po1 = wsb + 5898240L;
    __bf16* po2 = wsb + 11796480L;

    const bool split = (ws_size >= SPLIT_BYTES);

    convert_kernel<<<15840, 256, 0, stream>>>(x, wq, wk, wv, wo, xb);
    if (split) {
        qkv_kernel<<<dim3(16, 40, 2), 256, 0, stream>>>(
            xb, wqb, bq, wkb, bk, wvb, bv, qb, kb, vb, pq0, pk0, pv0, 1472, 1);
        reduce_rope_kernel<<<2560, 256, 0, stream>>>(
            qb, kb, vb, pq0, pk0, pv0, bq, bk, bv, rope);
    } else {
        qkv_kernel<<<dim3(16, 40, 1), 256, 0, stream>>>(
            xb, wqb, bq, wkb, bk, wvb, bv, qb, kb, vb, qb, kb, vb, 0, 0);
        rope_kernel<<<2304, 256, 0, stream>>>(qb, kb, rope);
    }
    attn_kernel<<<dim3(32, 64), 256, 0, stream>>>(qb, kb, vb, sk);
    oproj_kernel<<<dim3(16, 23, 3), 256, 0, stream>>>(qb, wob, po0, po1, po2);
    reduce3_kernel<<<2880, 256, 0, stream>>>(po0, po1, po2, bo, out);
}

// Round 7
// 343.051 us; speedup vs baseline: 1.0501x; 1.0501x over previous
//
#include <hip/hip_runtime.h>
#include <hip/hip_bf16.h>
#include <math.h>

// ---------------------------------------------------------------------------
// Attention_17231408791684: x->QKV (bias) -> RoPE -> sliding-window(128)
// causal attention w/ sinks -> O-proj (bias).  f32 in/out, bf16 compute.
// Round 7: revert r6 split-K qkv (proved occupancy not binding); RoPE fused
// into attention staging. 5 launches: convert, qkv, attn(+rope),
// oproj(split-K=2), reduce.
// ---------------------------------------------------------------------------

typedef __bf16 bf16x8 __attribute__((ext_vector_type(8)));
typedef float  f32x4  __attribute__((ext_vector_type(4)));

#define MFMA_BF16(a,b,c) __builtin_amdgcn_mfma_f32_16x16x32_bf16((a),(b),(c),0,0,0)

// workspace element offsets (bf16 elements)
#define XB   0L
#define WQB  5898240L
#define WKB  17694720L
#define WVB  19169280L
#define WOB  20643840L
#define QB   32440320L
#define KB   40828928L
#define VB   41877504L

__device__ __forceinline__ void gld_lds16(const void* g, void* l) {
    __builtin_amdgcn_global_load_lds(
        (__attribute__((address_space(1))) void*)(g),
        (__attribute__((address_space(3))) void*)(l), 16, 0, 0);
}

__device__ __forceinline__ bf16x8 ld8f(const float* p) {
    f32x4 a = *(const f32x4*)p;
    f32x4 b = *(const f32x4*)(p + 4);
    bf16x8 r;
#pragma unroll
    for (int t = 0; t < 4; t++) { r[t] = (__bf16)a[t]; r[t + 4] = (__bf16)b[t]; }
    return r;
}

// ---------------------------------------------------------------------------
// f32 -> bf16 conversion of {x, wq, wk, wv, wo}; 8 elems/thread, 15840x256.
// ---------------------------------------------------------------------------
__global__ __launch_bounds__(256) void convert_kernel(
    const float* __restrict__ x,  const float* __restrict__ wq,
    const float* __restrict__ wk, const float* __restrict__ wv,
    const float* __restrict__ wo, __bf16* __restrict__ dst)
{
    long e = ((long)blockIdx.x * 256 + threadIdx.x) * 8;
    const float* src; long off;
    if      (e <  WQB) { src = x;  off = e; }
    else if (e <  WKB) { src = wq; off = e - WQB; }
    else if (e <  WVB) { src = wk; off = e - WKB; }
    else if (e <  WOB) { src = wv; off = e - WVB; }
    else               { src = wo; off = e - WOB; }
    *(bf16x8*)(dst + e) = ld8f(src + off);
}

// ---------------------------------------------------------------------------
// NT GEMM, BK=64, k in [kBeg,kEnd). 128x128 tile, 256 thr (2x2 waves of
// 64x64). LDS [2][128][32]/operand. bias==nullptr -> none.
// ---------------------------------------------------------------------------
__device__ __forceinline__ void gemm_block64(
    const __bf16* __restrict__ A, const __bf16* __restrict__ W,
    const float* __restrict__ bias, __bf16* __restrict__ C,
    int N, int Ks, int kBeg, int kEnd, int m0, int n0,
    __bf16* As, __bf16* Bs)
{
    const int tid  = threadIdx.x;
    const int lane = tid & 63;
    const int wv   = tid >> 6;
    const int wm   = (wv >> 1) * 64;
    const int wn   = (wv & 1) * 64;
    const int quad = lane >> 4;
    const int c    = lane & 15;

    const int srow = tid >> 2;          // 0..63
    const int scol = (tid & 3) * 8;     // 0,8,16,24

    int br0 = n0 + srow;      if (br0 > N - 1) br0 = N - 1;
    int br1 = n0 + 64 + srow; if (br1 > N - 1) br1 = N - 1;
    const __bf16* pa0 = A + (size_t)(m0 + srow) * Ks + scol;
    const __bf16* pa1 = A + (size_t)(m0 + 64 + srow) * Ks + scol;
    const __bf16* pb0 = W + (size_t)br0 * Ks + scol;
    const __bf16* pb1 = W + (size_t)br1 * Ks + scol;

    f32x4 acc[4][4];
#pragma unroll
    for (int i = 0; i < 4; i++)
#pragma unroll
        for (int j = 0; j < 4; j++) acc[i][j] = (f32x4){0.f, 0.f, 0.f, 0.f};

    for (int kk = kBeg; kk < kEnd; kk += 64) {
        gld_lds16(pa0 + kk,      As + tid * 8);
        gld_lds16(pa1 + kk,      As + 2048 + tid * 8);
        gld_lds16(pa0 + kk + 32, As + 4096 + tid * 8);
        gld_lds16(pa1 + kk + 32, As + 6144 + tid * 8);
        gld_lds16(pb0 + kk,      Bs + tid * 8);
        gld_lds16(pb1 + kk,      Bs + 2048 + tid * 8);
        gld_lds16(pb0 + kk + 32, Bs + 4096 + tid * 8);
        gld_lds16(pb1 + kk + 32, Bs + 6144 + tid * 8);
        __syncthreads();
        for (int kt = 0; kt < 2; kt++) {
            bf16x8 af[4], bfv[4];
#pragma unroll
            for (int i = 0; i < 4; i++)
                af[i] = *(const bf16x8*)&As[kt * 4096 + (wm + i * 16 + c) * 32 + quad * 8];
#pragma unroll
            for (int j = 0; j < 4; j++)
                bfv[j] = *(const bf16x8*)&Bs[kt * 4096 + (wn + j * 16 + c) * 32 + quad * 8];
#pragma unroll
            for (int i = 0; i < 4; i++)
#pragma unroll
                for (int j = 0; j < 4; j++)
                    acc[i][j] = MFMA_BF16(af[i], bfv[j], acc[i][j]);
        }
        __syncthreads();
    }

#pragma unroll
    for (int j = 0; j < 4; j++) {
        int col = n0 + wn + j * 16 + c;
        if (col >= N) continue;
        float bv = bias ? bias[col] : 0.0f;
#pragma unroll
        for (int i = 0; i < 4; i++) {
            int row = m0 + wm + i * 16 + quad * 4;
#pragma unroll
            for (int r = 0; r < 4; r++)
                C[(size_t)(row + r) * N + col] = (__bf16)(acc[i][j][r] + bv);
        }
    }
}

// Fused QKV, whole-K: grid (16,40); by<32 -> q, by<36 -> k, else v.
__global__ __launch_bounds__(256, 3) void qkv_kernel(
    const __bf16* __restrict__ x,
    const __bf16* __restrict__ wq, const float* __restrict__ bq,
    const __bf16* __restrict__ wk, const float* __restrict__ bk,
    const __bf16* __restrict__ wv, const float* __restrict__ bv,
    __bf16* __restrict__ qo, __bf16* __restrict__ ko, __bf16* __restrict__ vo)
{
    __shared__ __align__(16) __bf16 As[8192], Bs[8192];
    const int by = blockIdx.y;
    const __bf16 *W; const float* bias; __bf16* C; int N, n0;
    if (by < 32)      { W = wq; bias = bq; C = qo; N = 4096; n0 = by * 128; }
    else if (by < 36) { W = wk; bias = bk; C = ko; N = 512;  n0 = (by - 32) * 128; }
    else              { W = wv; bias = bv; C = vo; N = 512;  n0 = (by - 36) * 128; }
    gemm_block64(x, W, bias, C, N, 2880, 0, 2880, blockIdx.x * 128, n0, As, Bs);
}

// O-proj split-K=2 partials: grid (16,23,2); k halves of 4096.
__global__ __launch_bounds__(256, 3) void oproj_kernel(
    const __bf16* __restrict__ a, const __bf16* __restrict__ w,
    __bf16* __restrict__ p0, __bf16* __restrict__ p1)
{
    __shared__ __align__(16) __bf16 As[8192], Bs[8192];
    const int z = blockIdx.z;
    __bf16* C = z ? p1 : p0;
    gemm_block64(a, w, nullptr, C, 2880, 4096, z * 2048, (z + 1) * 2048,
                 blockIdx.x * 128, blockIdx.y * 128, As, Bs);
}

// out[e] = p0[e] + p1[e] + bias[col]; 8 elems/thread, grid 2880x256 exact.
__global__ __launch_bounds__(256) void reduce_kernel(
    const __bf16* __restrict__ p0, const __bf16* __restrict__ p1,
    const float* __restrict__ bo, float* __restrict__ out)
{
    long e = ((long)blockIdx.x * 256 + threadIdx.x) * 8;
    int col = (int)(e % 2880L);          // 2880 % 8 == 0: no row crossing
    bf16x8 a = *(const bf16x8*)(p0 + e);
    bf16x8 b = *(const bf16x8*)(p1 + e);
    f32x4 o0, o1;
#pragma unroll
    for (int t = 0; t < 4; t++) {
        o0[t] = (float)a[t]     + (float)b[t]     + bo[col + t];
        o1[t] = (float)a[4 + t] + (float)b[4 + t] + bo[col + 4 + t];
    }
    *(f32x4*)(out + e)     = o0;
    *(f32x4*)(out + e + 4) = o1;
}

// ---------------------------------------------------------------------------
// Attention with FUSED RoPE, in-place on q. block = (64-query tile, head);
// RoPE (pair d, d+32; cos/sin halves duplicated in rope_cache) is applied
// while staging Q and K rows into LDS — q/k in global stay un-roped.
// Wave w owns q rows [w*16,w*16+16) x all 192 staged keys (k0 = i0-128).
// Softmax stats wave-local (shfl over the 16-lane c group).
// LDS: Qs[64][72]@0, Ks[192][72]@9216, Vt[64][208]@36864; P overlays @0.
// ---------------------------------------------------------------------------
__global__ __launch_bounds__(256) void attn_kernel(
    __bf16* __restrict__ q, const __bf16* __restrict__ k,
    const __bf16* __restrict__ v, const float* __restrict__ sinks,
    const float* __restrict__ rope)
{
    __shared__ __align__(16) char smem[63488];
    __bf16* Qs = (__bf16*)smem;                 // [64][72]
    __bf16* Ks = (__bf16*)(smem + 9216);        // [192][72]
    __bf16* Vt = (__bf16*)(smem + 36864);       // [64][208]
    __bf16* P  = (__bf16*)smem;                 // [64][208] overlay (post-QK^T)

    const int tid = threadIdx.x, lane = tid & 63, w = tid >> 6;
    const int quad = lane >> 4, c = lane & 15;
    const int i0 = blockIdx.x * 64;
    const int h  = blockIdx.y;
    const int kvh = h >> 3;
    const int k0 = i0 - 128;

    // ---- stage Q (rope), K (rope), V^T
    {
        const int srow = tid >> 2;          // 0..63
        const int dg   = (tid & 3) * 8;     // 0,8,16,24
        // Q row i0+srow, dims [dg,dg+8) and [dg+32,dg+40)
        {
            const __bf16* gp = q + (size_t)(i0 + srow) * 4096 + h * 64 + dg;
            bf16x8 x1 = *(const bf16x8*)(gp);
            bf16x8 x2 = *(const bf16x8*)(gp + 32);
            const float* rc = rope + (size_t)(i0 + srow) * 128 + dg;
            bf16x8 o1, o2;
#pragma unroll
            for (int t = 0; t < 8; t++) {
                float cc = rc[t], si = rc[64 + t];
                float a = (float)x1[t], b = (float)x2[t];
                o1[t] = (__bf16)(a * cc - b * si);
                o2[t] = (__bf16)(b * cc + a * si);
            }
            *(bf16x8*)&Qs[srow * 72 + dg]      = o1;
            *(bf16x8*)&Qs[srow * 72 + dg + 32] = o2;
        }
        // K rows: 192 x 4 units = 768 = 3 iterations
#pragma unroll
        for (int it = 0; it < 3; it++) {
            int unit = it * 256 + tid;
            int krow = unit >> 2;
            int kdg  = (unit & 3) * 8;
            int j = k0 + krow; if (j < 0) j = 0;
            const __bf16* gp = k + (size_t)j * 512 + kvh * 64 + kdg;
            bf16x8 x1 = *(const bf16x8*)(gp);
            bf16x8 x2 = *(const bf16x8*)(gp + 32);
            const float* rc = rope + (size_t)j * 128 + kdg;
            bf16x8 o1, o2;
#pragma unroll
            for (int t = 0; t < 8; t++) {
                float cc = rc[t], si = rc[64 + t];
                float a = (float)x1[t], b = (float)x2[t];
                o1[t] = (__bf16)(a * cc - b * si);
                o2[t] = (__bf16)(b * cc + a * si);
            }
            *(bf16x8*)&Ks[krow * 72 + kdg]      = o1;
            *(bf16x8*)&Ks[krow * 72 + kdg + 32] = o2;
        }
        // V transposed (no rope)
        const int vrow = tid & 31;
        const int d0 = (tid >> 5) * 8;
#pragma unroll
        for (int it = 0; it < 6; it++) {
            int r2 = vrow + it * 32;
            int j = k0 + r2; if (j < 0) j = 0;
            bf16x8 t = *(const bf16x8*)(v + (size_t)j * 512 + kvh * 64 + d0);
#pragma unroll
            for (int u = 0; u < 8; u++) Vt[(d0 + u) * 208 + r2] = t[u];
        }
    }
    __syncthreads();

    // ---- QK^T: wave w -> its 16 q rows x 192 keys (12 key tiles)
    f32x4 acc[12];
#pragma unroll
    for (int j = 0; j < 12; j++) acc[j] = (f32x4){0.f, 0.f, 0.f, 0.f};
#pragma unroll
    for (int kt = 0; kt < 2; kt++) {
        bf16x8 af = *(const bf16x8*)&Qs[(w * 16 + c) * 72 + kt * 32 + quad * 8];
#pragma unroll
        for (int j = 0; j < 12; j++) {
            bf16x8 bv = *(const bf16x8*)&Ks[(j * 16 + c) * 72 + kt * 32 + quad * 8];
            acc[j] = MFMA_BF16(af, bv, acc[j]);
        }
    }
    __syncthreads();   // all Qs/Ks reads done before P overlay writes

    // ---- mask + scale + wave-local softmax (rows quad*4+r of this wave)
    const float scale = 0.16832169878499658f;   // (0.1*ln32+1)/sqrt(64)
    const int igb = i0 + w * 16 + quad * 4;
    float rmax[4] = {-3.0e4f, -3.0e4f, -3.0e4f, -3.0e4f};
#pragma unroll
    for (int j = 0; j < 12; j++) {
        int jg = k0 + j * 16 + c;
#pragma unroll
        for (int r = 0; r < 4; r++) {
            int ig = igb + r;
            bool ok = (jg >= 0) && (jg <= ig) && (ig - jg < 128);
            float vv = ok ? acc[j][r] * scale : -3.0e4f;
            acc[j][r] = vv;
            rmax[r] = fmaxf(rmax[r], vv);
        }
    }
#pragma unroll
    for (int off = 1; off < 16; off <<= 1)
#pragma unroll
        for (int r = 0; r < 4; r++)
            rmax[r] = fmaxf(rmax[r], __shfl_xor(rmax[r], off));

    float rs[4] = {0.f, 0.f, 0.f, 0.f};
#pragma unroll
    for (int j = 0; j < 12; j++)
#pragma unroll
        for (int r = 0; r < 4; r++) {
            float e = __expf(acc[j][r] - rmax[r]);
            acc[j][r] = e;
            rs[r] += e;
        }
#pragma unroll
    for (int off = 1; off < 16; off <<= 1)
#pragma unroll
        for (int r = 0; r < 4; r++)
            rs[r] += __shfl_xor(rs[r], off);

    // rowfac = sigmoid(lse - sink) / rowsum   (diagonal valid => rs >= 1)
    float rowfac[4];
    {
        float sk = sinks[h];
#pragma unroll
        for (int r = 0; r < 4; r++) {
            float s = fmaxf(rs[r], 1e-20f);
            float lse = rmax[r] + __logf(s);
            rowfac[r] = 1.f / ((1.f + __expf(sk - lse)) * s);
        }
    }

    // ---- write P (bf16 probabilities), wave-local rows
#pragma unroll
    for (int j = 0; j < 12; j++)
#pragma unroll
        for (int r = 0; r < 4; r++)
            P[(w * 16 + quad * 4 + r) * 208 + j * 16 + c] = (__bf16)acc[j][r];
    __syncthreads();

    // ---- PV: wave w -> its 16 q rows x 64 dims, K=192
    f32x4 acc2[4];
#pragma unroll
    for (int jd = 0; jd < 4; jd++) acc2[jd] = (f32x4){0.f, 0.f, 0.f, 0.f};
#pragma unroll
    for (int kt = 0; kt < 6; kt++) {
        bf16x8 a = *(const bf16x8*)&P[(w * 16 + c) * 208 + kt * 32 + quad * 8];
#pragma unroll
        for (int jd = 0; jd < 4; jd++) {
            bf16x8 b = *(const bf16x8*)&Vt[(jd * 16 + c) * 208 + kt * 32 + quad * 8];
            acc2[jd] = MFMA_BF16(a, b, acc2[jd]);
        }
    }
#pragma unroll
    for (int jd = 0; jd < 4; jd++)
#pragma unroll
        for (int r = 0; r < 4; r++) {
            int qr = w * 16 + quad * 4 + r;
            q[(size_t)(i0 + qr) * 4096 + h * 64 + jd * 16 + c] =
                (__bf16)(acc2[jd][r] * rowfac[r]);
        }
}

// ---------------------------------------------------------------------------
extern "C" void kernel_launch(void* const* d_in, const int* in_sizes, int n_in,
                              void* d_out, int out_size, void* d_ws, size_t ws_size,
                              hipStream_t stream) {
    const float* x    = (const float*)d_in[0];
    const float* rope = (const float*)d_in[1];
    const float* wq   = (const float*)d_in[2];
    const float* bq   = (const float*)d_in[3];
    const float* wk   = (const float*)d_in[4];
    const float* bk   = (const float*)d_in[5];
    const float* wv   = (const float*)d_in[6];
    const float* bv   = (const float*)d_in[7];
    const float* wo   = (const float*)d_in[8];
    const float* bo   = (const float*)d_in[9];
    const float* sk   = (const float*)d_in[10];
    float* out = (float*)d_out;

    __bf16* wsb = (__bf16*)d_ws;
    __bf16* xb  = wsb + XB;
    __bf16* wqb = wsb + WQB;
    __bf16* wkb = wsb + WKB;
    __bf16* wvb = wsb + WVB;
    __bf16* wob = wsb + WOB;
    __bf16* qb  = wsb + QB;
    __bf16* kb  = wsb + KB;
    __bf16* vb  = wsb + VB;
    __bf16* po0 = wsb + 0L;            // oproj partials overlay dead xb/wqb
    __bf16* po1 = wsb + 5898240L;

    convert_kernel<<<15840, 256, 0, stream>>>(x, wq, wk, wv, wo, xb);
    qkv_kernel<<<dim3(16, 40), 256, 0, stream>>>(xb, wqb, bq, wkb, bk, wvb, bv,
                                                 qb, kb, vb);
    attn_kernel<<<dim3(32, 64), 256, 0, stream>>>(qb, kb, vb, sk, rope);
    oproj_kernel<<<dim3(16, 23, 2), 256, 0, stream>>>(qb, wob, po0, po1);
    reduce_kernel<<<2880, 256, 0, stream>>>(po0, po1, bo, out);
}